// Round 14
// baseline (57.566 us; speedup 1.0000x reference)
//
#include <hip/hip_runtime.h>

typedef _Float16 h2 __attribute__((ext_vector_type(2)));
typedef _Float16 h8 __attribute__((ext_vector_type(8)));
typedef float f4 __attribute__((ext_vector_type(4)));
typedef unsigned int uint32;

#define NVAL 20
#define CDIM 64
#define HW   65536
#define NPIX (4*HW)

#define BLK   1024
#define NWAVE (BLK/64)            // 16
#define MAXTILES 35               // sum ceil(n_k/64) <= 16 + 19 = 35
#define MAXSLOT  (MAXTILES*64)    // 2240

// ---- ws layout (bytes) ----
#define KN_OFF      0
#define KN_KSTRIDE  2560          // per class: 20 j-rows x 128 B (c-contig, normalized)
#define VAL_OFF     (20*KN_KSTRIDE)      // 51200
#define VAL_KSTRIDE 4096          // per class: 64 c-rows x 64 B (32 j-slots)
#define VAL_CSTRIDE 64
#define XROWS_OFF   (VAL_OFF + 20*VAL_KSTRIDE)   // 133120; NPIX x 128 B normalized f16 rows
#define WS_NEED     (XROWS_OFF + (size_t)NPIX*128)

// ---- LDS layout for gather kernel (bytes) ----
#define ROW_STRIDE 144            // W (64 B) then O (128 B) scratch per pixel
#define ROWS_BYTES (BLK*ROW_STRIDE)          // 147456
#define PERM_OFF  ROWS_BYTES                 // MAXSLOT u16 (4480)
#define TCLS_OFF  (PERM_OFF + MAXSLOT*2)
#define FLAG_OFF  (TCLS_OFF + 144)
#define CNT_OFF   (FLAG_OFF + 144)
#define LDS_TOTAL (CNT_OFF + 24*4 + 16)      // ~152.3 KB -> 1 block/CU

// ---- LDS layout for fallback kernel (r13, with staged X rows + invA) ----
#define FINV_OFF  ROWS_BYTES
#define FPERM_OFF (FINV_OFF + BLK*4)
#define FTCLS_OFF (FPERM_OFF + MAXSLOT*2)
#define FFLAG_OFF (FTCLS_OFF + 144)
#define FCNT_OFF  (FFLAG_OFF + 144)
#define FLDS_TOTAL (FCNT_OFF + 24*4 + 16)

static __device__ __forceinline__ h2 bch2(uint32 u) { return __builtin_bit_cast(h2, u); }
static __device__ __forceinline__ uint32 bcu(h2 v) { return __builtin_bit_cast(uint32, v); }
static __device__ __forceinline__ h8 bch8(uint4 u) { return __builtin_bit_cast(h8, u); }
static __device__ __forceinline__ h2 pkrtz(float a, float b) {
    return __builtin_bit_cast(h2, __builtin_amdgcn_cvt_pkrtz(a, b));
}

// ---------------------------------------------------------------------------
// Prep: build packed f16 tables in ws (unchanged, verified since round 5).
// ---------------------------------------------------------------------------
__global__ void prep_kernel(const float* __restrict__ key,
                            const float* __restrict__ val,
                            unsigned char* __restrict__ ws) {
    int i = blockIdx.x * 256 + threadIdx.x;
    if (i < 20*CDIM) {
        int k = i >> 6, c = i & 63;
        const float* vb = val + k*NVAL*CDIM + c;     // val[k][j][c]
        float v[NVAL];
        float s = 0.f;
        #pragma unroll
        for (int j = 0; j < NVAL; j++) { v[j] = vb[j*CDIM]; s += v[j]; }
        float t = 0.f;
        for (int kk = 0; kk < 20; kk++) {
            const float* vb2 = val + kk*NVAL*CDIM + c;
            #pragma unroll
            for (int j = 0; j < NVAL; j++) t += vb2[j*CDIM];
        }
        float rest = (t - s) * (1.0f/NVAL);
        uint32* row = (uint32*)(ws + VAL_OFF + (size_t)k*VAL_KSTRIDE + c*VAL_CSTRIDE);
        #pragma unroll
        for (int jp = 0; jp < 10; jp++) row[jp] = bcu(pkrtz(v[2*jp], v[2*jp+1]));
        row[10] = bcu(pkrtz(rest, 0.f));
        #pragma unroll
        for (int jp = 11; jp < 16; jp++) row[jp] = 0u;
    } else if (i < 20*CDIM + 20*NVAL) {
        int idx = i - 20*CDIM;
        int k = idx / NVAL, j = idx % NVAL;
        const float* kb = key + k*CDIM*NVAL + j;     // key[k][c][j]
        float x[CDIM];
        float ssq = 0.f;
        #pragma unroll
        for (int c = 0; c < CDIM; c++) { x[c] = kb[c*NVAL]; ssq = fmaf(x[c], x[c], ssq); }
        float inv = 1.0f / fmaxf(sqrtf(ssq), 1e-12f);
        uint32* row = (uint32*)(ws + KN_OFF + (size_t)k*KN_KSTRIDE + j*128);
        #pragma unroll
        for (int cp = 0; cp < 32; cp++) row[cp] = bcu(pkrtz(x[2*cp]*inv, x[2*cp+1]*inv));
    }
}

// every thread redundantly scans the 20 counters: {my_base_slot, n_tiles}
static __device__ __forceinline__ int2 scan20(const int* cnt, int cls) {
    int acc = 0, mb = 0;
    #pragma unroll
    for (int k = 1; k <= 20; k++) {
        if (k == cls) mb = acc;
        acc += (cnt[k] + 63) & ~63;
    }
    return make_int2(mb, acc >> 6);
}

// ---------------------------------------------------------------------------
// Kernel A: pure streaming normalize. Read 64 f32 planar (coalesced), write
// one 128 B pre-NORMALIZED f16 row per pixel into ws. No LDS, no barriers.
// ---------------------------------------------------------------------------
__global__ __launch_bounds__(256) void norm_kernel(
        const float* __restrict__ content, unsigned char* __restrict__ ws) {
    const int gpix = blockIdx.x * 256 + threadIdx.x;
    const int b = gpix >> 16, p = gpix & (HW - 1);
    const float* cptr = content + (size_t)b * CDIM * HW + p;
    float x[CDIM];
    float ssq = 0.f;
    #pragma unroll
    for (int c = 0; c < CDIM; c++) {
        x[c] = cptr[(size_t)c * HW];
        ssq = fmaf(x[c], x[c], ssq);
    }
    const float inv = 1.0f / fmaxf(sqrtf(ssq), 1e-12f);
    uint4* row = (uint4*)(ws + XROWS_OFF + (size_t)gpix * 128);
    #pragma unroll
    for (int q = 0; q < 8; q++) {
        uint4 o;
        o.x = bcu(pkrtz(x[8*q+0]*inv, x[8*q+1]*inv));
        o.y = bcu(pkrtz(x[8*q+2]*inv, x[8*q+3]*inv));
        o.z = bcu(pkrtz(x[8*q+4]*inv, x[8*q+5]*inv));
        o.w = bcu(pkrtz(x[8*q+6]*inv, x[8*q+7]*inv));
        row[q] = o;
    }
}

// ---------------------------------------------------------------------------
// Kernel B: 256 blocks x 1024 threads. Sort into class-pure 64-px wave-tiles;
// X fragments GATHERED from global pre-normalized rows inside the tile loop
// (full 128 B row consumed by the tile's lanes -> no line waste); softmax arg
// is the raw MFMA score (rows pre-normalized). W/O via LDS rows; per-tile
// flags + self-service coalesced store; XCD swizzle.
// ---------------------------------------------------------------------------
__global__ __launch_bounds__(BLK, 4) void gather_kernel(
        const int* __restrict__ seg, const unsigned char* __restrict__ tabs,
        float* __restrict__ out) {
    extern __shared__ unsigned char lds[];
    unsigned short* perm = (unsigned short*)(lds + PERM_OFF);
    int* tcls  = (int*)(lds + TCLS_OFF);
    int* flags = (int*)(lds + FLAG_OFF);
    int* cnt   = (int*)(lds + CNT_OFF);

    const int tid  = threadIdx.x;
    const int bid  = (int)((blockIdx.x & 7) * 32 + (blockIdx.x >> 3));  // XCD swizzle
    const int gp0  = bid * BLK;
    const int b    = gp0 >> 16;
    const int pim0 = gp0 & (HW - 1);
    float* obase = out + (size_t)b * CDIM * HW + pim0;
    const unsigned char* xrows = tabs + XROWS_OFF + (size_t)gp0 * 128;

    if (tid < 24) cnt[tid] = 0;
    if (tid < MAXTILES) flags[tid] = 0;
    for (int i = tid; i < MAXSLOT; i += BLK) perm[i] = 0xFFFFu;
    __syncthreads();

    const int cls = seg[gp0 + tid] + 1;          // 1..19
    const int myrank = atomicAdd(&cnt[cls], 1);
    __syncthreads();                              // histogram complete

    const int2 s = scan20(cnt, cls);              // (my base slot, n tiles)
    const int myslot = s.x + myrank;
    const int mytile = myslot >> 6;
    {
        perm[myslot] = (unsigned short)tid;
        tcls[mytile] = cls;                       // class-pure tile
    }
    __syncthreads();                              // perm/tcls complete

    const int nt   = s.y;
    const int wave = tid >> 6, lane = tid & 63;
    const int g = lane >> 4, r16 = lane & 15;

    for (int t = wave; t < nt; t += NWAVE) {
        const int u = __builtin_amdgcn_readfirstlane(tcls[t]);

        int rowb[4];
        bool mine[4];
        uint4 b_sc[4][2];
        #pragma unroll
        for (int n = 0; n < 4; n++) {
            int v = perm[t*64 + n*16 + r16];
            mine[n] = (v != 0xFFFF);
            int l = mine[n] ? v : 0;
            rowb[n] = l * ROW_STRIDE;
            // gather X fragments from global normalized rows (16 B each;
            // the 8 (g,ks)-lanes of a row consume all 128 B of it)
            const uint4* rp = (const uint4*)(xrows + (size_t)l * 128);
            b_sc[n][0] = rp[g];
            b_sc[n][1] = rp[4 + g];
        }

        // ---- scores S^T[j][p] = sum_c Kn^T[j][c] * Xn^T[c][p] ----
        const unsigned char* knc = tabs + KN_OFF + (size_t)u * KN_KSTRIDE;
        uint4 a_sc[2][2];
        #pragma unroll
        for (int m = 0; m < 2; m++)
            #pragma unroll
            for (int ks = 0; ks < 2; ks++)
                a_sc[m][ks] = *(const uint4*)(knc + (m*16 + r16)*128 + (ks*32 + g*8)*2);

        f4 sacc[2][4];
        #pragma unroll
        for (int m = 0; m < 2; m++)
            #pragma unroll
            for (int n = 0; n < 4; n++) sacc[m][n] = (f4){0.f,0.f,0.f,0.f};
        #pragma unroll
        for (int ks = 0; ks < 2; ks++)
            #pragma unroll
            for (int m = 0; m < 2; m++)
                #pragma unroll
                for (int n = 0; n < 4; n++)
                    sacc[m][n] = __builtin_amdgcn_mfma_f32_16x16x32_f16(
                        bch8(a_sc[m][ks]), bch8(b_sc[n][ks]), sacc[m][n], 0, 0, 0);

        // ---- softmax; lane holds j = m*16 + g*4 + r for pixel p = n*16+r16 ----
        uint2 w0[4], w1[4];
        #pragma unroll
        for (int n = 0; n < 4; n++) {
            float e0[4], e1[4];
            #pragma unroll
            for (int r = 0; r < 4; r++) e0[r] = __expf(sacc[0][n][r]);
            float arg1 = (g == 0) ? 1.0f : 0.0f;          // j>=20 masked
            #pragma unroll
            for (int r = 0; r < 4; r++) e1[r] = __expf(sacc[1][n][r] * arg1);
            float sum = e0[0]+e0[1]+e0[2]+e0[3];
            sum += (g == 0) ? (e1[0]+e1[1]+e1[2]+e1[3]) : 0.0f;
            sum += __shfl_xor(sum, 16, 64);
            sum += __shfl_xor(sum, 32, 64);
            float wsc = 1.0f / sum;
            w0[n].x = bcu(pkrtz(e0[0]*wsc, e0[1]*wsc));
            w0[n].y = bcu(pkrtz(e0[2]*wsc, e0[3]*wsc));
            uint2 t1;
            if (g == 0)      { t1.x = bcu(pkrtz(e1[0]*wsc, e1[1]*wsc));
                               t1.y = bcu(pkrtz(e1[2]*wsc, e1[3]*wsc)); }
            else if (g == 1) { t1.x = 0x00003C00u; t1.y = 0u; }  // j20=1.0 (rest)
            else             { t1.x = 0u; t1.y = 0u; }
            w1[n] = t1;
        }
        // write W into pixel's LDS scratch row: j-contiguous 32 f16 at offset 0
        #pragma unroll
        for (int n = 0; n < 4; n++) {
            if (mine[n]) {
                *(uint2*)(lds + rowb[n] + g*8)      = w0[n];
                *(uint2*)(lds + rowb[n] + 32 + g*8) = w1[n];
            }
        }

        // ---- PV O^T[c][p] = sum_j V^T[c][j] * W^T[j][p] (K=32) ----
        uint4 b_pv[4];
        #pragma unroll
        for (int n = 0; n < 4; n++)
            b_pv[n] = *(const uint4*)(lds + rowb[n] + g*16);
        const unsigned char* vc = tabs + VAL_OFF + (size_t)u * VAL_KSTRIDE;
        #pragma unroll
        for (int m = 0; m < 4; m++) {
            uint4 a = *(const uint4*)(vc + (m*16 + r16)*VAL_CSTRIDE + g*16);
            #pragma unroll
            for (int n = 0; n < 4; n++) {
                f4 o = (f4){0.f,0.f,0.f,0.f};
                o = __builtin_amdgcn_mfma_f32_16x16x32_f16(bch8(a), bch8(b_pv[n]), o, 0, 0, 0);
                uint2 ov; ov.x = bcu(pkrtz(o[0], o[1])); ov.y = bcu(pkrtz(o[2], o[3]));
                if (mine[n])
                    *(uint2*)(lds + rowb[n] + m*32 + g*8) = ov;  // c = m*16+g*4..+3
            }
        }

        __threadfence_block();
        if (lane == 0)
            __hip_atomic_store(&flags[t], 1, __ATOMIC_RELEASE, __HIP_MEMORY_SCOPE_WORKGROUP);
    }

    // self-service store: wait only for MY tile, then store own row (coalesced)
    while (__hip_atomic_load(&flags[mytile], __ATOMIC_ACQUIRE,
                             __HIP_MEMORY_SCOPE_WORKGROUP) == 0) {
        __builtin_amdgcn_s_sleep(1);
    }
    {
        const uint4* r4 = (const uint4*)(lds + tid * ROW_STRIDE);
        float* op = obase + tid;
        #pragma unroll
        for (int q = 0; q < 8; q++) {
            uint4 v = r4[q];
            h2 x = bch2(v.x), y = bch2(v.y), z = bch2(v.z), w = bch2(v.w);
            op[(size_t)(8*q+0) * HW] = (float)x[0];
            op[(size_t)(8*q+1) * HW] = (float)x[1];
            op[(size_t)(8*q+2) * HW] = (float)y[0];
            op[(size_t)(8*q+3) * HW] = (float)y[1];
            op[(size_t)(8*q+4) * HW] = (float)z[0];
            op[(size_t)(8*q+5) * HW] = (float)z[1];
            op[(size_t)(8*q+6) * HW] = (float)w[0];
            op[(size_t)(8*q+7) * HW] = (float)w[1];
        }
    }
}

// ---------------------------------------------------------------------------
// Fallback (ws too small): round-13 fused kernel, verified at 40.8 us.
// ---------------------------------------------------------------------------
__global__ __launch_bounds__(BLK, 4) void fb_kernel(
        const float* __restrict__ content, const int* __restrict__ seg,
        const unsigned char* __restrict__ tabs, float* __restrict__ out) {
    extern __shared__ unsigned char lds[];
    float* invA = (float*)(lds + FINV_OFF);
    unsigned short* perm = (unsigned short*)(lds + FPERM_OFF);
    int* tcls  = (int*)(lds + FTCLS_OFF);
    int* flags = (int*)(lds + FFLAG_OFF);
    int* cnt   = (int*)(lds + FCNT_OFF);

    const int tid  = threadIdx.x;
    const int bid  = (int)((blockIdx.x & 7) * 32 + (blockIdx.x >> 3));
    const int gp0  = bid * BLK;
    const int b    = gp0 >> 16;
    const int pim0 = gp0 & (HW - 1);
    float* obase = out + (size_t)b * CDIM * HW + pim0;

    if (tid < 24) cnt[tid] = 0;
    if (tid < MAXTILES) flags[tid] = 0;
    for (int i = tid; i < MAXSLOT; i += BLK) perm[i] = 0xFFFFu;
    __syncthreads();

    const int cls = seg[gp0 + tid] + 1;
    const int myrank = atomicAdd(&cnt[cls], 1);
    {
        const float* cptr = content + (size_t)b * CDIM * HW + pim0 + tid;
        uint2* myrow = (uint2*)(lds + tid * ROW_STRIDE);
        float ssq = 0.f;
        #pragma unroll
        for (int q = 0; q < 16; q++) {
            float f0 = cptr[(size_t)(4*q+0) * HW];
            float f1 = cptr[(size_t)(4*q+1) * HW];
            float f2 = cptr[(size_t)(4*q+2) * HW];
            float f3 = cptr[(size_t)(4*q+3) * HW];
            ssq = fmaf(f0,f0,ssq); ssq = fmaf(f1,f1,ssq);
            ssq = fmaf(f2,f2,ssq); ssq = fmaf(f3,f3,ssq);
            uint2 o; o.x = bcu(pkrtz(f0,f1)); o.y = bcu(pkrtz(f2,f3));
            myrow[q] = o;
        }
        invA[tid] = 1.0f / fmaxf(sqrtf(ssq), 1e-12f);
    }
    __syncthreads();

    const int2 s = scan20(cnt, cls);
    const int myslot = s.x + myrank;
    const int mytile = myslot >> 6;
    perm[myslot] = (unsigned short)tid;
    tcls[mytile] = cls;
    __syncthreads();

    const int nt   = s.y;
    const int wave = tid >> 6, lane = tid & 63;
    const int g = lane >> 4, r16 = lane & 15;

    for (int t = wave; t < nt; t += NWAVE) {
        const int u = __builtin_amdgcn_readfirstlane(tcls[t]);
        int rowb[4];
        float invn[4];
        bool mine[4];
        #pragma unroll
        for (int n = 0; n < 4; n++) {
            int v = perm[t*64 + n*16 + r16];
            mine[n] = (v != 0xFFFF);
            int l = mine[n] ? v : 0;
            rowb[n] = l * ROW_STRIDE;
            invn[n] = invA[l];
        }
        const unsigned char* knc = tabs + KN_OFF + (size_t)u * KN_KSTRIDE;
        uint4 a_sc[2][2];
        #pragma unroll
        for (int m = 0; m < 2; m++)
            #pragma unroll
            for (int ks = 0; ks < 2; ks++)
                a_sc[m][ks] = *(const uint4*)(knc + (m*16 + r16)*128 + (ks*32 + g*8)*2);
        uint4 b_sc[4][2];
        #pragma unroll
        for (int n = 0; n < 4; n++)
            #pragma unroll
            for (int ks = 0; ks < 2; ks++)
                b_sc[n][ks] = *(const uint4*)(lds + rowb[n] + (ks*32 + g*8)*2);
        f4 sacc[2][4];
        #pragma unroll
        for (int m = 0; m < 2; m++)
            #pragma unroll
            for (int n = 0; n < 4; n++) sacc[m][n] = (f4){0.f,0.f,0.f,0.f};
        #pragma unroll
        for (int ks = 0; ks < 2; ks++)
            #pragma unroll
            for (int m = 0; m < 2; m++)
                #pragma unroll
                for (int n = 0; n < 4; n++)
                    sacc[m][n] = __builtin_amdgcn_mfma_f32_16x16x32_f16(
                        bch8(a_sc[m][ks]), bch8(b_sc[n][ks]), sacc[m][n], 0, 0, 0);
        uint2 w0[4], w1[4];
        #pragma unroll
        for (int n = 0; n < 4; n++) {
            float e0[4], e1[4];
            #pragma unroll
            for (int r = 0; r < 4; r++) e0[r] = __expf(sacc[0][n][r] * invn[n]);
            float arg1 = (g == 0) ? invn[n] : 0.0f;
            #pragma unroll
            for (int r = 0; r < 4; r++) e1[r] = __expf(sacc[1][n][r] * arg1);
            float sum = e0[0]+e0[1]+e0[2]+e0[3];
            sum += (g == 0) ? (e1[0]+e1[1]+e1[2]+e1[3]) : 0.0f;
            sum += __shfl_xor(sum, 16, 64);
            sum += __shfl_xor(sum, 32, 64);
            float wsc = 1.0f / sum;
            w0[n].x = bcu(pkrtz(e0[0]*wsc, e0[1]*wsc));
            w0[n].y = bcu(pkrtz(e0[2]*wsc, e0[3]*wsc));
            uint2 t1;
            if (g == 0)      { t1.x = bcu(pkrtz(e1[0]*wsc, e1[1]*wsc));
                               t1.y = bcu(pkrtz(e1[2]*wsc, e1[3]*wsc)); }
            else if (g == 1) { t1.x = 0x00003C00u; t1.y = 0u; }
            else             { t1.x = 0u; t1.y = 0u; }
            w1[n] = t1;
        }
        #pragma unroll
        for (int n = 0; n < 4; n++) {
            if (mine[n]) {
                *(uint2*)(lds + rowb[n] + g*8)      = w0[n];
                *(uint2*)(lds + rowb[n] + 32 + g*8) = w1[n];
            }
        }
        uint4 b_pv[4];
        #pragma unroll
        for (int n = 0; n < 4; n++)
            b_pv[n] = *(const uint4*)(lds + rowb[n] + g*16);
        const unsigned char* vc = tabs + VAL_OFF + (size_t)u * VAL_KSTRIDE;
        #pragma unroll
        for (int m = 0; m < 4; m++) {
            uint4 a = *(const uint4*)(vc + (m*16 + r16)*VAL_CSTRIDE + g*16);
            #pragma unroll
            for (int n = 0; n < 4; n++) {
                f4 o = (f4){0.f,0.f,0.f,0.f};
                o = __builtin_amdgcn_mfma_f32_16x16x32_f16(bch8(a), bch8(b_pv[n]), o, 0, 0, 0);
                uint2 ov; ov.x = bcu(pkrtz(o[0], o[1])); ov.y = bcu(pkrtz(o[2], o[3]));
                if (mine[n])
                    *(uint2*)(lds + rowb[n] + m*32 + g*8) = ov;
            }
        }
        __threadfence_block();
        if (lane == 0)
            __hip_atomic_store(&flags[t], 1, __ATOMIC_RELEASE, __HIP_MEMORY_SCOPE_WORKGROUP);
    }
    while (__hip_atomic_load(&flags[mytile], __ATOMIC_ACQUIRE,
                             __HIP_MEMORY_SCOPE_WORKGROUP) == 0) {
        __builtin_amdgcn_s_sleep(1);
    }
    {
        const uint4* r4 = (const uint4*)(lds + tid * ROW_STRIDE);
        float* op = obase + tid;
        #pragma unroll
        for (int q = 0; q < 8; q++) {
            uint4 v = r4[q];
            h2 x = bch2(v.x), y = bch2(v.y), z = bch2(v.z), w = bch2(v.w);
            op[(size_t)(8*q+0) * HW] = (float)x[0];
            op[(size_t)(8*q+1) * HW] = (float)x[1];
            op[(size_t)(8*q+2) * HW] = (float)y[0];
            op[(size_t)(8*q+3) * HW] = (float)y[1];
            op[(size_t)(8*q+4) * HW] = (float)z[0];
            op[(size_t)(8*q+5) * HW] = (float)z[1];
            op[(size_t)(8*q+6) * HW] = (float)w[0];
            op[(size_t)(8*q+7) * HW] = (float)w[1];
        }
    }
}

extern "C" void kernel_launch(void* const* d_in, const int* in_sizes, int n_in,
                              void* d_out, int out_size, void* d_ws, size_t ws_size,
                              hipStream_t stream) {
    const float* content = (const float*)d_in[0];
    const int*   seg     = (const int*)d_in[1];
    const float* key     = (const float*)d_in[2];
    const float* val     = (const float*)d_in[3];
    float* out = (float*)d_out;
    unsigned char* ws = (unsigned char*)d_ws;

    prep_kernel<<<7, 256, 0, stream>>>(key, val, ws);

    if (ws_size >= WS_NEED) {
        norm_kernel<<<NPIX/256, 256, 0, stream>>>(content, ws);
        (void)hipFuncSetAttribute((const void*)gather_kernel,
                                  hipFuncAttributeMaxDynamicSharedMemorySize, LDS_TOTAL);
        gather_kernel<<<NPIX/BLK, BLK, LDS_TOTAL, stream>>>(seg, ws, out);
    } else {
        (void)hipFuncSetAttribute((const void*)fb_kernel,
                                  hipFuncAttributeMaxDynamicSharedMemorySize, FLDS_TOTAL);
        fb_kernel<<<NPIX/BLK, BLK, FLDS_TOTAL, stream>>>(content, seg, ws, out);
    }
}

// Round 15
// 40.126 us; speedup vs baseline: 1.4346x; 1.4346x over previous
//
#include <hip/hip_runtime.h>

typedef _Float16 h2 __attribute__((ext_vector_type(2)));
typedef _Float16 h8 __attribute__((ext_vector_type(8)));
typedef float f4 __attribute__((ext_vector_type(4)));
typedef unsigned int uint32;

#define NVAL 20
#define CDIM 64
#define HW   65536
#define NPIX (4*HW)

#define BLK   1024
#define NWAVE (BLK/64)            // 16
#define MAXTILES 35               // sum ceil(n_k/64) <= 16 + 19 = 35
#define MAXSLOT  (MAXTILES*64)    // 2240

// ---- packed f16 tables in ws (bytes) ----
#define KN_OFF      0
#define KN_KSTRIDE  2560          // per class: 20 j-rows x 128 B (c-contig, normalized)
#define VAL_OFF     (20*KN_KSTRIDE)      // 51200
#define VAL_KSTRIDE 4096          // per class: 64 c-rows x 64 B (32 j-slots)
#define VAL_CSTRIDE 64

// ---- LDS layout (bytes) ----
#define ROW_STRIDE 144            // 64 f16 (128 B) + 16 pad; 16B-aligned rows
#define ROWS_BYTES (BLK*ROW_STRIDE)          // 147456
#define INV_OFF   ROWS_BYTES                 // BLK f32 (4096)
#define PERM_OFF  (INV_OFF + BLK*4)          // MAXSLOT u16 (4480)
#define TCLS_OFF  (PERM_OFF + MAXSLOT*2)
#define FLAG_OFF  (TCLS_OFF + 144)
#define CNT_OFF   (FLAG_OFF + 144)
#define LDS_TOTAL (CNT_OFF + 24*4 + 16)      // ~152.8 KB -> 1 block/CU

static __device__ __forceinline__ h2 bch2(uint32 u) { return __builtin_bit_cast(h2, u); }
static __device__ __forceinline__ uint32 bcu(h2 v) { return __builtin_bit_cast(uint32, v); }
static __device__ __forceinline__ h8 bch8(uint4 u) { return __builtin_bit_cast(h8, u); }
static __device__ __forceinline__ h2 pkrtz(float a, float b) {
    return __builtin_bit_cast(h2, __builtin_amdgcn_cvt_pkrtz(a, b));
}

// ---------------------------------------------------------------------------
// Prep: build packed f16 tables in ws (unchanged, verified since round 5).
// ---------------------------------------------------------------------------
__global__ void prep_kernel(const float* __restrict__ key,
                            const float* __restrict__ val,
                            unsigned char* __restrict__ ws) {
    int i = blockIdx.x * 256 + threadIdx.x;
    if (i < 20*CDIM) {
        int k = i >> 6, c = i & 63;
        const float* vb = val + k*NVAL*CDIM + c;     // val[k][j][c]
        float v[NVAL];
        float s = 0.f;
        #pragma unroll
        for (int j = 0; j < NVAL; j++) { v[j] = vb[j*CDIM]; s += v[j]; }
        float t = 0.f;
        for (int kk = 0; kk < 20; kk++) {
            const float* vb2 = val + kk*NVAL*CDIM + c;
            #pragma unroll
            for (int j = 0; j < NVAL; j++) t += vb2[j*CDIM];
        }
        float rest = (t - s) * (1.0f/NVAL);
        uint32* row = (uint32*)(ws + VAL_OFF + (size_t)k*VAL_KSTRIDE + c*VAL_CSTRIDE);
        #pragma unroll
        for (int jp = 0; jp < 10; jp++) row[jp] = bcu(pkrtz(v[2*jp], v[2*jp+1]));
        row[10] = bcu(pkrtz(rest, 0.f));
        #pragma unroll
        for (int jp = 11; jp < 16; jp++) row[jp] = 0u;
    } else if (i < 20*CDIM + 20*NVAL) {
        int idx = i - 20*CDIM;
        int k = idx / NVAL, j = idx % NVAL;
        const float* kb = key + k*CDIM*NVAL + j;     // key[k][c][j]
        float x[CDIM];
        float ssq = 0.f;
        #pragma unroll
        for (int c = 0; c < CDIM; c++) { x[c] = kb[c*NVAL]; ssq = fmaf(x[c], x[c], ssq); }
        float inv = 1.0f / fmaxf(sqrtf(ssq), 1e-12f);
        uint32* row = (uint32*)(ws + KN_OFF + (size_t)k*KN_KSTRIDE + j*128);
        #pragma unroll
        for (int cp = 0; cp < 32; cp++) row[cp] = bcu(pkrtz(x[2*cp]*inv, x[2*cp+1]*inv));
    }
}

// every thread redundantly scans the 20 counters: {my_base_slot, n_tiles}
static __device__ __forceinline__ int2 scan20(const int* cnt, int cls) {
    int acc = 0, mb = 0;
    #pragma unroll
    for (int k = 1; k <= 20; k++) {
        if (k == cls) mb = acc;
        acc += (cnt[k] + 63) & ~63;
    }
    return make_int2(mb, acc >> 6);
}

// ---------------------------------------------------------------------------
// Main: 256 blocks x 1024 threads (1 block/CU, 16 waves). Round-13 structure.
// Deltas vs r13 (both latency-chain fixes, no structural change):
//  - stage loads batched 2x32 with separated load/consume loops -> ~32 planar
//    loads in flight per thread instead of ~4-8 (MLP fix)
//  - the 4 V-table (a_pv) fragments hoisted to tile top as named registers,
//    removing an L1-miss from the post-softmax critical path of every tile
// ---------------------------------------------------------------------------
__global__ __launch_bounds__(BLK, 4) void main_kernel(
        const float* __restrict__ content, const int* __restrict__ seg,
        const unsigned char* __restrict__ tabs, float* __restrict__ out) {
    extern __shared__ unsigned char lds[];
    float* invA = (float*)(lds + INV_OFF);
    unsigned short* perm = (unsigned short*)(lds + PERM_OFF);
    int* tcls  = (int*)(lds + TCLS_OFF);
    int* flags = (int*)(lds + FLAG_OFF);
    int* cnt   = (int*)(lds + CNT_OFF);

    const int tid  = threadIdx.x;
    const int bid  = (int)((blockIdx.x & 7) * 32 + (blockIdx.x >> 3));  // XCD swizzle
    const int gp0  = bid * BLK;
    const int b    = gp0 >> 16;
    const int pim0 = gp0 & (HW - 1);
    float* obase = out + (size_t)b * CDIM * HW + pim0;

    if (tid < 24) cnt[tid] = 0;
    if (tid < MAXTILES) flags[tid] = 0;
    for (int i = tid; i < MAXSLOT; i += BLK) perm[i] = 0xFFFFu;
    __syncthreads();

    const int cls = seg[gp0 + tid] + 1;          // 1..19
    const int myrank = atomicAdd(&cnt[cls], 1);

    // stage content -> own LDS row (f16 pairs, unnormalized) + inv.
    // Batched: 32 loads issued back-to-back, THEN consumed (MLP fix).
    {
        const float* cptr = content + (size_t)b * CDIM * HW + pim0 + tid;
        uint2* myrow = (uint2*)(lds + tid * ROW_STRIDE);
        float ssq = 0.f;
        #pragma unroll
        for (int h = 0; h < 2; h++) {
            float xb[32];
            #pragma unroll
            for (int j = 0; j < 32; j++) xb[j] = cptr[(size_t)(h*32 + j) * HW];
            #pragma unroll
            for (int j = 0; j < 32; j++) ssq = fmaf(xb[j], xb[j], ssq);
            #pragma unroll
            for (int q = 0; q < 8; q++) {
                uint2 o;
                o.x = bcu(pkrtz(xb[4*q+0], xb[4*q+1]));
                o.y = bcu(pkrtz(xb[4*q+2], xb[4*q+3]));
                myrow[h*8 + q] = o;
            }
        }
        invA[tid] = 1.0f / fmaxf(sqrtf(ssq), 1e-12f);
    }
    __syncthreads();                              // cnt + rows + inv complete

    const int2 s = scan20(cnt, cls);              // (my base slot, n tiles)
    const int myslot = s.x + myrank;
    const int mytile = myslot >> 6;
    {
        perm[myslot] = (unsigned short)tid;
        tcls[mytile] = cls;                       // class-pure tile
    }
    __syncthreads();                              // perm/tcls complete

    const int nt   = s.y;
    const int wave = tid >> 6, lane = tid & 63;
    const int g = lane >> 4, r16 = lane & 15;

    for (int t = wave; t < nt; t += NWAVE) {
        const int u = __builtin_amdgcn_readfirstlane(tcls[t]);

        int rowb[4];
        float invn[4];
        bool mine[4];
        #pragma unroll
        for (int n = 0; n < 4; n++) {
            int v = perm[t*64 + n*16 + r16];
            mine[n] = (v != 0xFFFF);
            int l = mine[n] ? v : 0;
            rowb[n] = l * ROW_STRIDE;
            invn[n] = invA[l];
        }

        // ---- issue ALL table loads for this tile up front (named regs) ----
        const unsigned char* knc = tabs + KN_OFF + (size_t)u * KN_KSTRIDE;
        const unsigned char* vc  = tabs + VAL_OFF + (size_t)u * VAL_KSTRIDE;
        uint4 a_sc[2][2];
        #pragma unroll
        for (int m = 0; m < 2; m++)
            #pragma unroll
            for (int ks = 0; ks < 2; ks++)
                a_sc[m][ks] = *(const uint4*)(knc + (m*16 + r16)*128 + (ks*32 + g*8)*2);
        uint4 apv0 = *(const uint4*)(vc + (0*16 + r16)*VAL_CSTRIDE + g*16);
        uint4 apv1 = *(const uint4*)(vc + (1*16 + r16)*VAL_CSTRIDE + g*16);
        uint4 apv2 = *(const uint4*)(vc + (2*16 + r16)*VAL_CSTRIDE + g*16);
        uint4 apv3 = *(const uint4*)(vc + (3*16 + r16)*VAL_CSTRIDE + g*16);

        uint4 b_sc[4][2];
        #pragma unroll
        for (int n = 0; n < 4; n++)
            #pragma unroll
            for (int ks = 0; ks < 2; ks++)
                b_sc[n][ks] = *(const uint4*)(lds + rowb[n] + (ks*32 + g*8)*2);

        // ---- scores S^T[j][p] = sum_c Kn^T[j][c] * X^T[c][p] ----
        f4 sacc[2][4];
        #pragma unroll
        for (int m = 0; m < 2; m++)
            #pragma unroll
            for (int n = 0; n < 4; n++) sacc[m][n] = (f4){0.f,0.f,0.f,0.f};
        #pragma unroll
        for (int ks = 0; ks < 2; ks++)
            #pragma unroll
            for (int m = 0; m < 2; m++)
                #pragma unroll
                for (int n = 0; n < 4; n++)
                    sacc[m][n] = __builtin_amdgcn_mfma_f32_16x16x32_f16(
                        bch8(a_sc[m][ks]), bch8(b_sc[n][ks]), sacc[m][n], 0, 0, 0);

        // ---- softmax; lane holds j = m*16 + g*4 + r for pixel p = n*16+r16 ----
        uint2 w0[4], w1[4];
        #pragma unroll
        for (int n = 0; n < 4; n++) {
            float e0[4], e1[4];
            #pragma unroll
            for (int r = 0; r < 4; r++) e0[r] = __expf(sacc[0][n][r] * invn[n]);
            float arg1 = (g == 0) ? invn[n] : 0.0f;     // j>=20 masked
            #pragma unroll
            for (int r = 0; r < 4; r++) e1[r] = __expf(sacc[1][n][r] * arg1);
            float sum = e0[0]+e0[1]+e0[2]+e0[3];
            sum += (g == 0) ? (e1[0]+e1[1]+e1[2]+e1[3]) : 0.0f;
            sum += __shfl_xor(sum, 16, 64);
            sum += __shfl_xor(sum, 32, 64);
            float wsc = 1.0f / sum;
            w0[n].x = bcu(pkrtz(e0[0]*wsc, e0[1]*wsc));
            w0[n].y = bcu(pkrtz(e0[2]*wsc, e0[3]*wsc));
            uint2 t1;
            if (g == 0)      { t1.x = bcu(pkrtz(e1[0]*wsc, e1[1]*wsc));
                               t1.y = bcu(pkrtz(e1[2]*wsc, e1[3]*wsc)); }
            else if (g == 1) { t1.x = 0x00003C00u; t1.y = 0u; }  // j20=1.0 (rest)
            else             { t1.x = 0u; t1.y = 0u; }
            w1[n] = t1;
        }
        // write W over own row (X is dead): j-contiguous 32 f16 at offset 0
        #pragma unroll
        for (int n = 0; n < 4; n++) {
            if (mine[n]) {
                *(uint2*)(lds + rowb[n] + g*8)      = w0[n];
                *(uint2*)(lds + rowb[n] + 32 + g*8) = w1[n];
            }
        }

        // ---- PV O^T[c][p] = sum_j V^T[c][j] * W^T[j][p] (K=32) ----
        uint4 b_pv[4];
        #pragma unroll
        for (int n = 0; n < 4; n++)
            b_pv[n] = *(const uint4*)(lds + rowb[n] + g*16);
        #pragma unroll
        for (int m = 0; m < 4; m++) {
            uint4 a = (m == 0) ? apv0 : (m == 1) ? apv1 : (m == 2) ? apv2 : apv3;
            #pragma unroll
            for (int n = 0; n < 4; n++) {
                f4 o = (f4){0.f,0.f,0.f,0.f};
                o = __builtin_amdgcn_mfma_f32_16x16x32_f16(bch8(a), bch8(b_pv[n]), o, 0, 0, 0);
                uint2 ov; ov.x = bcu(pkrtz(o[0], o[1])); ov.y = bcu(pkrtz(o[2], o[3]));
                if (mine[n])
                    *(uint2*)(lds + rowb[n] + m*32 + g*8) = ov;  // c = m*16+g*4..+3
            }
        }

        // tile t complete: publish (O rows of its 64 pixels are final)
        __threadfence_block();
        if (lane == 0)
            __hip_atomic_store(&flags[t], 1, __ATOMIC_RELEASE, __HIP_MEMORY_SCOPE_WORKGROUP);
    }

    // self-service store: wait only for MY tile, then store own row (coalesced)
    while (__hip_atomic_load(&flags[mytile], __ATOMIC_ACQUIRE,
                             __HIP_MEMORY_SCOPE_WORKGROUP) == 0) {
        __builtin_amdgcn_s_sleep(1);
    }
    {
        const uint4* r4 = (const uint4*)(lds + tid * ROW_STRIDE);
        float* op = obase + tid;
        #pragma unroll
        for (int q = 0; q < 8; q++) {
            uint4 v = r4[q];
            h2 x = bch2(v.x), y = bch2(v.y), z = bch2(v.z), w = bch2(v.w);
            op[(size_t)(8*q+0) * HW] = (float)x[0];
            op[(size_t)(8*q+1) * HW] = (float)x[1];
            op[(size_t)(8*q+2) * HW] = (float)y[0];
            op[(size_t)(8*q+3) * HW] = (float)y[1];
            op[(size_t)(8*q+4) * HW] = (float)z[0];
            op[(size_t)(8*q+5) * HW] = (float)z[1];
            op[(size_t)(8*q+6) * HW] = (float)w[0];
            op[(size_t)(8*q+7) * HW] = (float)w[1];
        }
    }
}

extern "C" void kernel_launch(void* const* d_in, const int* in_sizes, int n_in,
                              void* d_out, int out_size, void* d_ws, size_t ws_size,
                              hipStream_t stream) {
    const float* content = (const float*)d_in[0];
    const int*   seg     = (const int*)d_in[1];
    const float* key     = (const float*)d_in[2];
    const float* val     = (const float*)d_in[3];
    float* out = (float*)d_out;
    unsigned char* ws = (unsigned char*)d_ws;

    prep_kernel<<<7, 256, 0, stream>>>(key, val, ws);

    (void)hipFuncSetAttribute((const void*)main_kernel,
                              hipFuncAttributeMaxDynamicSharedMemorySize, LDS_TOTAL);
    main_kernel<<<NPIX/BLK, BLK, LDS_TOTAL, stream>>>(content, seg, ws, out);
}